// Round 6
// baseline (82.002 us; speedup 1.0000x reference)
//
#include <hip/hip_runtime.h>
#include <float.h>

#define FH 64
#define FW 64
#define FC 256
#define NB 4
#define NR 128
#define NREG 32
#define POOLH 3
#define POOLW 3
#define IOU_THR 0.4f
#define NCELL (POOLH * POOLW)
#define MAXPIX 160   // max cell pixels: last band <= 12 -> 12*12=144, padded

#define POOLED_ELEMS (NB * NREG * NCELL * FC)

// Python floor-division semantics for /2 on possibly-negative ints.
__device__ inline void fix_axis(int mn, int mx, int ps, int fs, int& omin, int& omax) {
    int pad = ps - (mx - mn);
    bool fix_min = mn < (pad >> 1);
    bool fix_max = (fs - mx) < ((1 + pad) >> 1);
    bool sym = (pad > 0) && !(fix_min || fix_max);
    omin = sym ? (mn - (pad >> 1)) : mn;
    omax = sym ? (mx + ((1 + pad) >> 1)) : mx;
    if ((pad > 0) && fix_min) { omin = 0; omax = ps; }
    if ((pad > 0) && fix_max) { omin = fs - ps; omax = fs; }
}

__device__ inline float4 max4(float4 a, float4 b) {
    float4 o;
    o.x = fmaxf(a.x, b.x); o.y = fmaxf(a.y, b.y);
    o.z = fmaxf(a.z, b.z); o.w = fmaxf(a.w, b.w);
    return o;
}

// Broadcast lane `lane`'s 64-bit value to all lanes (lane must be wave-uniform).
__device__ inline unsigned long long readlane64(unsigned long long v, int lane) {
    unsigned lo = (unsigned)__builtin_amdgcn_readlane((int)(unsigned)v, lane);
    unsigned hi = (unsigned)__builtin_amdgcn_readlane((int)(unsigned)(v >> 32), lane);
    return ((unsigned long long)hi << 32) | lo;
}

// One block per (region, pool-cell). Bitmask NMS (wave 1 skips its provably
// all-zero rows), ALL-wave register-row resolve (no barrier, no idle waves),
// then float4 pooling with 4-way pixel split + 8 loads in flight.
__global__ __launch_bounds__(256) void fused_kernel(
    const float* __restrict__ features,  // (B, H, W, C)
    const float* __restrict__ roi,       // (B, R, 4)
    float* __restrict__ out)             // pooled (B,32,3,3,C) ++ roi_clipped (B,32,4)
{
    // XCD batch-affinity swizzle: consecutive hw block IDs round-robin the 8
    // XCDs (id & 7). Batch b's 288 blocks land on XCD pair {2b, 2b+1} so its
    // 4 MB feature slab stays resident in 8 MB of paired L2.
    const int hwid = blockIdx.x;
    const int b = (hwid >> 1) & 3;
    const int j = (hwid >> 3) * 2 + (hwid & 1);   // 0..287 within batch
    const int r = j / NCELL;                      // region 0..31
    const int cell = j - r * NCELL;               // 0..8
    const int ci = cell / POOLW, cj = cell - ci * POOLW;
    const int reg = b * NREG + r;
    const int tid = threadIdx.x;
    const int wid = tid >> 6;                     // wave id = pixel group
    const int lane = tid & 63;

    __shared__ float sx1[NR], sy1[NR], sx2[NR], sy2[NR], sarea[NR];
    __shared__ unsigned long long smask[NR][2];   // [64..127][0] never written/read
    __shared__ int spix[MAXPIX];
    __shared__ float4 sred[4][64];

    // Load this batch's boxes
    if (tid < NR) {
        const float4 bx = *(const float4*)(roi + ((size_t)b * NR + tid) * 4);
        sx1[tid] = bx.x; sy1[tid] = bx.y;
        sx2[tid] = bx.x + bx.z; sy2[tid] = bx.y + bx.w;
        sarea[tid] = bx.z * bx.w;
    }
    __syncthreads();

    // Row-build. Wave 0: rows 0..63 half 0; wave 2: rows 0..63 half 1;
    // wave 3: rows 64..127 half 1. Wave 1 would build rows 64..127 half 0 —
    // provably all zero (no j>p with j<64, p>=64) and never read: skip.
    if (wid != 1) {
        const int p = tid & 127;
        const int half = tid >> 7;
        const int j0 = half << 6;
        const float px1 = sx1[p], py1 = sy1[p], px2 = sx2[p], py2 = sy2[p], pa = sarea[p];
        unsigned long long m = 0ull;
        #pragma unroll 8
        for (int t = 0; t < 64; ++t) {
            const int jj = j0 + t;
            float iw = fmaxf(fminf(px2, sx2[jj]) - fmaxf(px1, sx1[jj]), 0.0f);
            float ih = fmaxf(fminf(py2, sy2[jj]) - fmaxf(py1, sy1[jj]), 0.0f);
            float inter = iw * ih;
            bool sup = (jj > p) && (inter > IOU_THR * (pa + sarea[jj] - inter));
            m |= ((unsigned long long)sup) << t;
        }
        smask[p][half] = m;
    }
    __syncthreads();

    // ALL-wave resolve: each wave holds rows in its own registers and scans
    // kept bits (a box still set when reached is final-kept; stop at 32).
    // Everything in the scan is wave-uniform -> no divergence, no barrier.
    const unsigned long long aLo = smask[lane][0];       // row lane, bits [0,64)
    const unsigned long long aHi = smask[lane][1];       // row lane, bits [64,128)
    const unsigned long long bHi = smask[lane + 64][1];  // row lane+64, bits [64,128)

    int idx = NR - 1;
    {
        unsigned long long k1 = ~0ull;
        int cnt = 0;
        unsigned long long cur = ~0ull;      // half-0 candidates
        while (cur && cnt < NREG) {
            int p = __ffsll((unsigned long long)cur) - 1;
            if (cnt == r) idx = p;
            ++cnt;
            int ps = __builtin_amdgcn_readfirstlane(p);
            unsigned long long m0 = readlane64(aLo, ps);
            unsigned long long m1 = readlane64(aHi, ps);
            cur = (cur & (cur - 1)) & ~m0;
            k1 &= ~m1;
        }
        cur = k1;
        while (cur && cnt < NREG) {
            int p = __ffsll((unsigned long long)cur) - 1;
            if (cnt == r) idx = 64 + p;
            ++cnt;
            int ps = __builtin_amdgcn_readfirstlane(p);
            unsigned long long m1 = readlane64(bHi, ps);
            cur = (cur & (cur - 1)) & ~m1;
        }
    }

    // Clip (all lanes, wave-uniform; sx2 = x1+w exactly matches reference x+w).
    int xmn, xmx, ymn, ymx;
    {
        float x1 = sx1[idx], y1 = sy1[idx], x2f = sx2[idx], y2f = sy2[idx];
        int x_min = (int)fmaxf(0.0f, x1);
        int y_min = (int)fmaxf(0.0f, y1);
        int x_max = (int)fminf((float)FW, x2f);
        int y_max = (int)fminf((float)FH, y2f);
        fix_axis(x_min, x_max, POOLW, FW, xmn, xmx);
        fix_axis(y_min, y_max, POOLH, FH, ymn, ymx);
    }
    if (tid == 0 && cell == 0) {
        float* orc = out + POOLED_ELEMS + ((size_t)reg) * 4;
        orc[0] = (float)xmn;
        orc[1] = (float)ymn;
        orc[2] = (float)(xmx - xmn);
        orc[3] = (float)(ymx - ymn);
    }

    // Cell bounds (registers, all threads agree)
    const int x = xmn, y = ymn, w = xmx - xmn, h = ymx - ymn;
    const int hh = h / POOLH;
    const int ww = w / POOLW;
    const int r0 = y + ci * hh;
    const int r1 = (ci < POOLH - 1) ? (y + (ci + 1) * hh) : (y + h);
    const int c0 = x + cj * ww;
    const int c1 = (cj < POOLW - 1) ? (x + (cj + 1) * ww) : (x + w);
    const int ncols = c1 - c0;
    const int n = (r1 - r0) * ncols;          // 1..144

    // Pixel offsets (channel-independent)
    if (tid < n) {
        int q = tid / ncols;
        int cc = tid - q * ncols;
        spix[tid] = ((r0 + q) * FW + (c0 + cc)) * FC;
    }
    __syncthreads();

    // Pooling: lane owns channels [4*lane, 4*lane+4). Wave g takes pixels
    // k = g, g+4, ...; batches of 8 keep 8 loads in flight.
    const float* fbase = features + (size_t)b * FH * FW * FC;
    const float4 negv = {-FLT_MAX, -FLT_MAX, -FLT_MAX, -FLT_MAX};
    float4 m0 = negv, m1 = negv, m2 = negv, m3 = negv;
    float4 m4 = negv, m5 = negv, m6 = negv, m7 = negv;
    int k = wid;
    for (; k + 28 < n; k += 32) {
        int o0 = spix[k],      o1 = spix[k + 4],  o2 = spix[k + 8],  o3 = spix[k + 12];
        int o4 = spix[k + 16], o5 = spix[k + 20], o6 = spix[k + 24], o7 = spix[k + 28];
        float4 v0 = ((const float4*)(fbase + o0))[lane];
        float4 v1 = ((const float4*)(fbase + o1))[lane];
        float4 v2 = ((const float4*)(fbase + o2))[lane];
        float4 v3 = ((const float4*)(fbase + o3))[lane];
        float4 v4 = ((const float4*)(fbase + o4))[lane];
        float4 v5 = ((const float4*)(fbase + o5))[lane];
        float4 v6 = ((const float4*)(fbase + o6))[lane];
        float4 v7 = ((const float4*)(fbase + o7))[lane];
        m0 = max4(m0, v0); m1 = max4(m1, v1); m2 = max4(m2, v2); m3 = max4(m3, v3);
        m4 = max4(m4, v4); m5 = max4(m5, v5); m6 = max4(m6, v6); m7 = max4(m7, v7);
    }
    for (; k + 12 < n; k += 16) {
        int o0 = spix[k], o1 = spix[k + 4], o2 = spix[k + 8], o3 = spix[k + 12];
        float4 v0 = ((const float4*)(fbase + o0))[lane];
        float4 v1 = ((const float4*)(fbase + o1))[lane];
        float4 v2 = ((const float4*)(fbase + o2))[lane];
        float4 v3 = ((const float4*)(fbase + o3))[lane];
        m0 = max4(m0, v0); m1 = max4(m1, v1); m2 = max4(m2, v2); m3 = max4(m3, v3);
    }
    for (; k < n; k += 4) {
        float4 v = ((const float4*)(fbase + spix[k]))[lane];
        m0 = max4(m0, v);
    }
    m0 = max4(max4(m0, m1), max4(m2, m3));
    m4 = max4(max4(m4, m5), max4(m6, m7));
    sred[wid][lane] = max4(m0, m4);
    __syncthreads();

    // Final reduce over the 4 waves; coalesced float4 store.
    if (tid < 64) {
        float4 a = max4(max4(sred[0][tid], sred[1][tid]),
                        max4(sred[2][tid], sred[3][tid]));
        float4* ob = (float4*)(out + ((size_t)reg * NCELL + cell) * FC);
        ob[tid] = a;
    }
}

extern "C" void kernel_launch(void* const* d_in, const int* in_sizes, int n_in,
                              void* d_out, int out_size, void* d_ws, size_t ws_size,
                              hipStream_t stream) {
    const float* features = (const float*)d_in[0];  // (4, 64, 64, 256) f32
    const float* roi = (const float*)d_in[1];       // (4, 128, 4) f32
    float* out = (float*)d_out;                     // 294912 + 512 f32 elems
    (void)in_sizes; (void)n_in; (void)out_size; (void)d_ws; (void)ws_size;

    fused_kernel<<<NB * NREG * NCELL, 256, 0, stream>>>(features, roi, out);
}

// Round 7
// 80.486 us; speedup vs baseline: 1.0188x; 1.0188x over previous
//
#include <hip/hip_runtime.h>
#include <float.h>

#define FH 64
#define FW 64
#define FC 256
#define NB 4
#define NR 128
#define NREG 32
#define POOLH 3
#define POOLW 3
#define IOU_THR 0.4f
#define NCELL (POOLH * POOLW)
#define MAXPIX 160   // max cell pixels: last band <= 12 -> 12*12=144, padded

#define POOLED_ELEMS (NB * NREG * NCELL * FC)

// Python floor-division semantics for /2 on possibly-negative ints.
__device__ inline void fix_axis(int mn, int mx, int ps, int fs, int& omin, int& omax) {
    int pad = ps - (mx - mn);
    bool fix_min = mn < (pad >> 1);
    bool fix_max = (fs - mx) < ((1 + pad) >> 1);
    bool sym = (pad > 0) && !(fix_min || fix_max);
    omin = sym ? (mn - (pad >> 1)) : mn;
    omax = sym ? (mx + ((1 + pad) >> 1)) : mx;
    if ((pad > 0) && fix_min) { omin = 0; omax = ps; }
    if ((pad > 0) && fix_max) { omin = fs - ps; omax = fs; }
}

__device__ inline float4 max4(float4 a, float4 b) {
    float4 o;
    o.x = fmaxf(a.x, b.x); o.y = fmaxf(a.y, b.y);
    o.z = fmaxf(a.z, b.z); o.w = fmaxf(a.w, b.w);
    return o;
}

// Broadcast lane `lane`'s 64-bit value to all lanes (lane must be wave-uniform).
__device__ inline unsigned long long readlane64(unsigned long long v, int lane) {
    unsigned lo = (unsigned)__builtin_amdgcn_readlane((int)(unsigned)v, lane);
    unsigned hi = (unsigned)__builtin_amdgcn_readlane((int)(unsigned)(v >> 32), lane);
    return ((unsigned long long)hi << 32) | lo;
}

// One block per (region, pool-cell). Bitmask NMS (wave 1 skips its provably
// all-zero rows), all-wave register-row resolve with EARLY EXIT at rank r,
// self-owned spix slots (no barrier), float4 pooling with 8 loads in flight.
__global__ __launch_bounds__(256) void fused_kernel(
    const float* __restrict__ features,  // (B, H, W, C)
    const float* __restrict__ roi,       // (B, R, 4)
    float* __restrict__ out)             // pooled (B,32,3,3,C) ++ roi_clipped (B,32,4)
{
    // XCD batch-affinity swizzle: consecutive hw block IDs round-robin the 8
    // XCDs (id & 7). Batch b's 288 blocks land on XCD pair {2b, 2b+1} so its
    // 4 MB feature slab stays resident in 8 MB of paired L2.
    const int hwid = blockIdx.x;
    const int b = (hwid >> 1) & 3;
    const int j = (hwid >> 3) * 2 + (hwid & 1);   // 0..287 within batch
    const int r = j / NCELL;                      // region 0..31
    const int cell = j - r * NCELL;               // 0..8
    const int ci = cell / POOLW, cj = cell - ci * POOLW;
    const int reg = b * NREG + r;
    const int tid = threadIdx.x;
    const int wid = tid >> 6;                     // wave id = pixel group
    const int lane = tid & 63;

    __shared__ float sx1[NR], sy1[NR], sx2[NR], sy2[NR], sarea[NR];
    __shared__ unsigned long long smask[NR][2];   // [64..127][0] never written/read
    __shared__ int spix[MAXPIX];
    __shared__ float4 sred[4][64];

    // Load this batch's boxes
    if (tid < NR) {
        const float4 bx = *(const float4*)(roi + ((size_t)b * NR + tid) * 4);
        sx1[tid] = bx.x; sy1[tid] = bx.y;
        sx2[tid] = bx.x + bx.z; sy2[tid] = bx.y + bx.w;
        sarea[tid] = bx.z * bx.w;
    }
    __syncthreads();

    // Row-build. Wave 0: rows 0..63 half 0; wave 2: rows 0..63 half 1;
    // wave 3: rows 64..127 half 1. Wave 1's rows (64..127, half 0) are
    // provably all zero (no j>p with j<64, p>=64) and never read: skip.
    if (wid != 1) {
        const int p = tid & 127;
        const int half = tid >> 7;
        const int j0 = half << 6;
        const float px1 = sx1[p], py1 = sy1[p], px2 = sx2[p], py2 = sy2[p], pa = sarea[p];
        unsigned long long m = 0ull;
        #pragma unroll 8
        for (int t = 0; t < 64; ++t) {
            const int jj = j0 + t;
            float iw = fmaxf(fminf(px2, sx2[jj]) - fmaxf(px1, sx1[jj]), 0.0f);
            float ih = fmaxf(fminf(py2, sy2[jj]) - fmaxf(py1, sy1[jj]), 0.0f);
            float inter = iw * ih;
            bool sup = (jj > p) && (inter > IOU_THR * (pa + sarea[jj] - inter));
            m |= ((unsigned long long)sup) << t;
        }
        smask[p][half] = m;
    }
    __syncthreads();

    // All-wave resolve with early exit: scan kept bits in ascending order
    // (a box still set when reached is final-kept); stop as soon as rank r
    // is identified. Wave-uniform throughout -> no divergence, no barrier.
    const unsigned long long aLo = smask[lane][0];       // row lane, bits [0,64)
    const unsigned long long aHi = smask[lane][1];       // row lane, bits [64,128)
    const unsigned long long bHi = smask[lane + 64][1];  // row lane+64, bits [64,128)

    int idx = NR - 1;
    {
        unsigned long long k1 = ~0ull;
        int cnt = 0;
        bool done = false;
        unsigned long long cur = ~0ull;      // half-0 candidates
        while (cur && cnt <= r) {
            int p = __ffsll((unsigned long long)cur) - 1;
            if (cnt == r) { idx = p; done = true; break; }
            ++cnt;
            int ps = __builtin_amdgcn_readfirstlane(p);
            unsigned long long m0 = readlane64(aLo, ps);
            unsigned long long m1 = readlane64(aHi, ps);
            cur = (cur & (cur - 1)) & ~m0;
            k1 &= ~m1;
        }
        if (!done) {
            cur = k1;
            while (cur && cnt <= r) {
                int p = __ffsll((unsigned long long)cur) - 1;
                if (cnt == r) { idx = 64 + p; break; }
                ++cnt;
                int ps = __builtin_amdgcn_readfirstlane(p);
                unsigned long long m1 = readlane64(bHi, ps);
                cur = (cur & (cur - 1)) & ~m1;
            }
        }
    }

    // Clip (all lanes, wave-uniform; sx2 = x1+w exactly matches reference x+w).
    int xmn, xmx, ymn, ymx;
    {
        float x1 = sx1[idx], y1 = sy1[idx], x2f = sx2[idx], y2f = sy2[idx];
        int x_min = (int)fmaxf(0.0f, x1);
        int y_min = (int)fmaxf(0.0f, y1);
        int x_max = (int)fminf((float)FW, x2f);
        int y_max = (int)fminf((float)FH, y2f);
        fix_axis(x_min, x_max, POOLW, FW, xmn, xmx);
        fix_axis(y_min, y_max, POOLH, FH, ymn, ymx);
    }
    if (tid == 0 && cell == 0) {
        float* orc = out + POOLED_ELEMS + ((size_t)reg) * 4;
        orc[0] = (float)xmn;
        orc[1] = (float)ymn;
        orc[2] = (float)(xmx - xmn);
        orc[3] = (float)(ymx - ymn);
    }

    // Cell bounds (registers, all threads agree)
    const int x = xmn, y = ymn, w = xmx - xmn, h = ymx - ymn;
    const int hh = h / POOLH;
    const int ww = w / POOLW;
    const int r0 = y + ci * hh;
    const int r1 = (ci < POOLH - 1) ? (y + (ci + 1) * hh) : (y + h);
    const int c0 = x + cj * ww;
    const int c1 = (cj < POOLW - 1) ? (x + (cj + 1) * ww) : (x + w);
    const int ncols = c1 - c0;
    const int n = (r1 - r0) * ncols;          // 1..144

    // Self-owned pixel offsets: wave g reads only slots k ≡ g (mod 4), so
    // lane t of wave g writes exactly k = g + 4t. Intra-wave dependency only
    // -> NO barrier needed before the pool loop.
    {
        const int k0i = wid + 4 * lane;
        if (k0i < n) {
            int q = k0i / ncols;
            int cc = k0i - q * ncols;
            spix[k0i] = ((r0 + q) * FW + (c0 + cc)) * FC;
        }
    }

    // Pooling: lane owns channels [4*lane, 4*lane+4). Wave g takes pixels
    // k = g, g+4, ...; batches of 8 keep 8 loads in flight.
    const float* fbase = features + (size_t)b * FH * FW * FC;
    const float4 negv = {-FLT_MAX, -FLT_MAX, -FLT_MAX, -FLT_MAX};
    float4 m0 = negv, m1 = negv, m2 = negv, m3 = negv;
    float4 m4 = negv, m5 = negv, m6 = negv, m7 = negv;
    int k = wid;
    for (; k + 28 < n; k += 32) {
        int o0 = spix[k],      o1 = spix[k + 4],  o2 = spix[k + 8],  o3 = spix[k + 12];
        int o4 = spix[k + 16], o5 = spix[k + 20], o6 = spix[k + 24], o7 = spix[k + 28];
        float4 v0 = ((const float4*)(fbase + o0))[lane];
        float4 v1 = ((const float4*)(fbase + o1))[lane];
        float4 v2 = ((const float4*)(fbase + o2))[lane];
        float4 v3 = ((const float4*)(fbase + o3))[lane];
        float4 v4 = ((const float4*)(fbase + o4))[lane];
        float4 v5 = ((const float4*)(fbase + o5))[lane];
        float4 v6 = ((const float4*)(fbase + o6))[lane];
        float4 v7 = ((const float4*)(fbase + o7))[lane];
        m0 = max4(m0, v0); m1 = max4(m1, v1); m2 = max4(m2, v2); m3 = max4(m3, v3);
        m4 = max4(m4, v4); m5 = max4(m5, v5); m6 = max4(m6, v6); m7 = max4(m7, v7);
    }
    for (; k + 12 < n; k += 16) {
        int o0 = spix[k], o1 = spix[k + 4], o2 = spix[k + 8], o3 = spix[k + 12];
        float4 v0 = ((const float4*)(fbase + o0))[lane];
        float4 v1 = ((const float4*)(fbase + o1))[lane];
        float4 v2 = ((const float4*)(fbase + o2))[lane];
        float4 v3 = ((const float4*)(fbase + o3))[lane];
        m0 = max4(m0, v0); m1 = max4(m1, v1); m2 = max4(m2, v2); m3 = max4(m3, v3);
    }
    for (; k < n; k += 4) {
        float4 v = ((const float4*)(fbase + spix[k]))[lane];
        m0 = max4(m0, v);
    }
    m0 = max4(max4(m0, m1), max4(m2, m3));
    m4 = max4(max4(m4, m5), max4(m6, m7));
    sred[wid][lane] = max4(m0, m4);
    __syncthreads();

    // Final reduce over the 4 waves; coalesced float4 store.
    if (tid < 64) {
        float4 a = max4(max4(sred[0][tid], sred[1][tid]),
                        max4(sred[2][tid], sred[3][tid]));
        float4* ob = (float4*)(out + ((size_t)reg * NCELL + cell) * FC);
        ob[tid] = a;
    }
}

extern "C" void kernel_launch(void* const* d_in, const int* in_sizes, int n_in,
                              void* d_out, int out_size, void* d_ws, size_t ws_size,
                              hipStream_t stream) {
    const float* features = (const float*)d_in[0];  // (4, 64, 64, 256) f32
    const float* roi = (const float*)d_in[1];       // (4, 128, 4) f32
    float* out = (float*)d_out;                     // 294912 + 512 f32 elems
    (void)in_sizes; (void)n_in; (void)out_size; (void)d_ws; (void)ws_size;

    fused_kernel<<<NB * NREG * NCELL, 256, 0, stream>>>(features, roi, out);
}